// Round 17
// baseline (3032.988 us; speedup 1.0000x reference)
//
#include <hip/hip_runtime.h>

// Residual VQ — bf16-MFMA screen + np-exact rescore. Round 17: LEVEL-
// SYNCHRONIZED kernels. r16's wall was cbf screen-load latency at L3 class:
// level-drifted blocks put 2-3 levels x 1.5 MB on each XCD's 4 MB L2 ->
// thrash. One kernel per level => all blocks read the SAME 1.5 MB (cbf
// level + f32 cb level) => L2-resident screen loads (~200 cyc). Residual
// lives in out[0:N*D] (f32, bit-exact) between levels; level 0 reads latent,
// level 7 writes straight-through in place. Decision arithmetic byte-
// identical to r14-r16 PASS.
//
// Screen: s~ = C_k - 2*(r~.c~) via mfma_f32_16x16x32_bf16 (RNE bf16).
// Rescore: np-exact chain: dot = sequential fmaf d=0..255 ascending,
// dist = fl(fl(A - fl(2 dot)) + C), lex (dist,k) min == np first-index ties.
// Safety: list overflow / screen-vs-exact alarm -> full exact scan.

#define NTOK 131072
#define DEPTH 8
#define KCB 1024
#define DIM 256
#define TM 16
#define RP 260
#define RBP 264
#define WWIN 0.2f
#define ALARM 0.05f
#define LCAP 64

typedef __attribute__((ext_vector_type(8))) short short8v;
typedef __attribute__((ext_vector_type(4))) float f32x4;

__device__ __forceinline__ unsigned short f32_to_bf16_rne(float f) {
  unsigned int u = __float_as_uint(f);
  return (unsigned short)((u + 0x7FFFu + ((u >> 16) & 1u)) >> 16);
}

__device__ __forceinline__ float np_sumsq_128(const float* p) {
  float s[16];
#pragma unroll
  for (int l = 0; l < 16; ++l) {
    float r0 = __fadd_rn(__fmul_rn(p[l], p[l]),
                         __fmul_rn(p[l + 64], p[l + 64]));
    float r1 = __fadd_rn(__fmul_rn(p[l + 16], p[l + 16]),
                         __fmul_rn(p[l + 80], p[l + 80]));
    float r2 = __fadd_rn(__fmul_rn(p[l + 32], p[l + 32]),
                         __fmul_rn(p[l + 96], p[l + 96]));
    float r3 = __fadd_rn(__fmul_rn(p[l + 48], p[l + 48]),
                         __fmul_rn(p[l + 112], p[l + 112]));
    s[l] = __fadd_rn(__fadd_rn(r0, r1), __fadd_rn(r2, r3));
  }
  float t[8];
#pragma unroll
  for (int l = 0; l < 8; ++l) t[l] = __fadd_rn(s[l], s[l + 8]);
  float u[4];
#pragma unroll
  for (int l = 0; l < 4; ++l) u[l] = __fadd_rn(t[l], t[l + 4]);
  return __fadd_rn(__fadd_rn(u[0], u[2]), __fadd_rn(u[1], u[3]));
}

__device__ __forceinline__ float np_sumsq_256(const float* p) {
  return __fadd_rn(np_sumsq_128(p), np_sumsq_128(p + 128));
}

__device__ __forceinline__ float np_dist(const float* rrow, const float* crow,
                                         float A, float C) {
  float dot = 0.f;
#pragma unroll 8
  for (int q = 0; q < 64; ++q) {
    float4 rv = *(const float4*)(rrow + q * 4);
    float4 cv = *(const float4*)(crow + q * 4);
    dot = fmaf(rv.x, cv.x, dot);
    dot = fmaf(rv.y, cv.y, dot);
    dot = fmaf(rv.z, cv.z, dot);
    dot = fmaf(rv.w, cv.w, dot);
  }
  return __fadd_rn(__fsub_rn(A, __fmul_rn(2.0f, dot)), C);
}

__global__ __launch_bounds__(256) void c2_kernel(const float* __restrict__ cbs,
                                                 float* __restrict__ C32g) {
  int gid = blockIdx.x * 256 + threadIdx.x;
  C32g[gid] = np_sumsq_256(cbs + (size_t)gid * DIM);
}

// cbf[(((lvl*64+g)*8+s)*64+lane)*8 + j] = bf16(cbs[lvl][g*16+(lane&15)]
//                                              [s*32+(lane>>4)*8+j])
__global__ __launch_bounds__(256) void pack_kernel(
    const float* __restrict__ cbs, unsigned short* __restrict__ cbf) {
  int gid = blockIdx.x * 256 + threadIdx.x;  // 262144
  int lane = gid & 63;
  int s = (gid >> 6) & 7;
  int g = (gid >> 9) & 63;
  int lvl = gid >> 15;
  int kcol = g * 16 + (lane & 15);
  int kd0 = s * 32 + (lane >> 4) * 8;
  const float* src = cbs + ((size_t)lvl * KCB + kcol) * DIM + kd0;
  unsigned short t[8];
#pragma unroll
  for (int j = 0; j < 8; ++j) t[j] = f32_to_bf16_rne(src[j]);
  ushort4 lo = {t[0], t[1], t[2], t[3]};
  ushort4 hi = {t[4], t[5], t[6], t[7]};
  *(ushort4*)(cbf + (size_t)gid * 8) = lo;
  *(ushort4*)(cbf + (size_t)gid * 8 + 4) = hi;
}

// One level. rsrc: residual source rows (latent for lvl 0, rbuf otherwise).
// lvl<7: write updated r to rbuf. lvl==7: write straight-through to rbuf
// (rbuf == out[0:N*D]) using latent.
__global__ __launch_bounds__(256, 3) void rvq_level_kernel(
    const float* __restrict__ latent, const float* __restrict__ cbs,
    const float* __restrict__ C32g, const unsigned short* __restrict__ cbf,
    float* __restrict__ rbuf, float* __restrict__ codes_out, int lvl) {
  __shared__ float r_m[TM][RP];
  __shared__ __align__(16) unsigned short rb[TM * RBP];
  __shared__ float A_s[TM];
  __shared__ float smin_s[4][TM];
  __shared__ float gmin_s[TM];
  __shared__ int cnt[TM];
  __shared__ int list[TM][LCAP];
  __shared__ int idx_s[TM];

  const int tid = threadIdx.x;
  const int w = tid >> 6;
  const int lane = tid & 63;
  const int lc = lane & 15;
  const int lg = lane >> 4;
  const int n0 = blockIdx.x * TM;
  const float* cb = cbs + (size_t)lvl * KCB * DIM;

  // ---- stage r (exact f32) + rb (bf16) ----
  {
    int tok = tid >> 4;
    int db = (tid & 15) * 16;
    const float* src =
        (lvl == 0 ? latent : rbuf) + (size_t)(n0 + tok) * DIM + db;
#pragma unroll
    for (int j = 0; j < 4; ++j) {
      float4 v = *(const float4*)(src + j * 4);
      *(float4*)&r_m[tok][db + j * 4] = v;
      rb[tok * RBP + db + j * 4 + 0] = f32_to_bf16_rne(v.x);
      rb[tok * RBP + db + j * 4 + 1] = f32_to_bf16_rne(v.y);
      rb[tok * RBP + db + j * 4 + 2] = f32_to_bf16_rne(v.z);
      rb[tok * RBP + db + j * 4 + 3] = f32_to_bf16_rne(v.w);
    }
  }
  __syncthreads();

  // exact A (np pairwise)
  if (tid < TM) A_s[tid] = np_sumsq_256(&r_m[tid][0]);

  f32x4 acc[8];
#pragma unroll 1
  for (int p = 0; p < 2; ++p) {
#pragma unroll
    for (int nt = 0; nt < 8; ++nt) acc[nt] = (f32x4){0.f, 0.f, 0.f, 0.f};
    {
      const unsigned short* bbase =
          cbf + ((((size_t)lvl * 64 + p * 32 + w * 8) * 8) * 64 + lane) * 8;
#pragma unroll
      for (int s = 0; s < 8; ++s) {
        short8v a0 = *(const short8v*)&rb[lc * RBP + s * 32 + lg * 8];
        const unsigned short* bp = bbase + (size_t)s * 64 * 8;
#pragma unroll
        for (int nt = 0; nt < 8; ++nt) {
          short8v bv = *(const short8v*)(bp + (size_t)nt * 8 * 64 * 8);
          acc[nt] =
              __builtin_amdgcn_mfma_f32_16x16x32_bf16(a0, bv, acc[nt], 0, 0, 0);
        }
      }
    }
    float tmin[4];
#pragma unroll
    for (int reg = 0; reg < 4; ++reg) tmin[reg] = 3.4e38f;
#pragma unroll
    for (int nt = 0; nt < 8; ++nt) {
      float Cv = C32g[lvl * KCB + (p * 32 + w * 8 + nt) * 16 + lc];
      f32x4 sc;
#pragma unroll
      for (int reg = 0; reg < 4; ++reg) {
        float v = __fsub_rn(Cv, __fmul_rn(2.0f, acc[nt][reg]));
        sc[reg] = v;
        tmin[reg] = fminf(tmin[reg], v);
      }
      acc[nt] = sc;
    }
#pragma unroll
    for (int m = 1; m <= 8; m <<= 1)
#pragma unroll
      for (int reg = 0; reg < 4; ++reg)
        tmin[reg] = fminf(tmin[reg], __shfl_xor(tmin[reg], m));
    if (lc == 0) {
#pragma unroll
      for (int reg = 0; reg < 4; ++reg) smin_s[w][lg * 4 + reg] = tmin[reg];
    }
    __syncthreads();

    if (tid < TM) {
      float g = smin_s[0][tid];
#pragma unroll
      for (int ww = 1; ww < 4; ++ww) g = fminf(g, smin_s[ww][tid]);
      if (p == 0) {
        gmin_s[tid] = g;
        cnt[tid] = 0;
      } else {
        gmin_s[tid] = fminf(gmin_s[tid], g);
      }
    }
    __syncthreads();

#pragma unroll
    for (int reg = 0; reg < 4; ++reg) {
      int t = lg * 4 + reg;
      float th = gmin_s[t] + WWIN;
#pragma unroll
      for (int nt = 0; nt < 8; ++nt) {
        if (acc[nt][reg] <= th) {
          int slot = atomicAdd(&cnt[t], 1);
          if (slot < LCAP) list[t][slot] = (p * 32 + w * 8 + nt) * 16 + lc;
        }
      }
    }
    __syncthreads();
  }

  // ---- np-exact rescore (16 threads per token) ----
  {
    int t = tid >> 4;
    int kc = tid & 15;
    float A = A_s[t];
    int n = cnt[t];
    float bd = 3.4e38f;
    int bk = KCB;
    if (n <= LCAP) {
      for (int ci = kc; ci < n; ci += 16) {
        int k = list[t][ci];
        float d = np_dist(&r_m[t][0], cb + (size_t)k * DIM, A,
                          C32g[lvl * KCB + k]);
        if (d < bd || (d == bd && k < bk)) {
          bd = d;
          bk = k;
        }
      }
    }
#pragma unroll
    for (int m = 1; m <= 8; m <<= 1) {
      float od = __shfl_xor(bd, m);
      int ok = __shfl_xor(bk, m);
      if (od < bd || (od == bd && ok < bk)) {
        bd = od;
        bk = ok;
      }
    }
    bool redo =
        (n > LCAP) || (fabsf(__fsub_rn(bd, A) - gmin_s[t]) > (WWIN - ALARM));
    if (redo) {
      bd = 3.4e38f;
      bk = KCB;
      for (int k = kc; k < KCB; k += 16) {
        float d = np_dist(&r_m[t][0], cb + (size_t)k * DIM, A,
                          C32g[lvl * KCB + k]);
        if (d < bd || (d == bd && k < bk)) {
          bd = d;
          bk = k;
        }
      }
#pragma unroll
      for (int m = 1; m <= 8; m <<= 1) {
        float od = __shfl_xor(bd, m);
        int ok = __shfl_xor(bk, m);
        if (od < bd || (od == bd && ok < bk)) {
          bd = od;
          bk = ok;
        }
      }
    }
    if (kc == 0) {
      idx_s[t] = bk;
      codes_out[(size_t)lvl * NTOK + n0 + t] = (float)bk;
    }
  }
  __syncthreads();

  // ---- residual update r = fl(r - c[idx]) + writeback ----
  {
    int tok = tid >> 4;
    int db = (tid & 15) * 16;
    const float* crow = cb + (size_t)idx_s[tok] * DIM + db;
    size_t gi = (size_t)(n0 + tok) * DIM + db;
    if (lvl < DEPTH - 1) {
#pragma unroll
      for (int j = 0; j < 4; ++j) {
        float4 cv4 = *(const float4*)(crow + j * 4);
        float4 rv = *(const float4*)&r_m[tok][db + j * 4];
        float4 x;
        x.x = __fsub_rn(rv.x, cv4.x);
        x.y = __fsub_rn(rv.y, cv4.y);
        x.z = __fsub_rn(rv.z, cv4.z);
        x.w = __fsub_rn(rv.w, cv4.w);
        *(float4*)(rbuf + gi + j * 4) = x;
      }
    } else {
      // final level: ST = fl(l + fl(q - l)), q = fl(l - r_final)
#pragma unroll
      for (int j = 0; j < 4; ++j) {
        float4 cv4 = *(const float4*)(crow + j * 4);
        float4 rv = *(const float4*)&r_m[tok][db + j * 4];
        float4 rf;
        rf.x = __fsub_rn(rv.x, cv4.x);
        rf.y = __fsub_rn(rv.y, cv4.y);
        rf.z = __fsub_rn(rv.z, cv4.z);
        rf.w = __fsub_rn(rv.w, cv4.w);
        float4 l4 = *(const float4*)(latent + gi + j * 4);
        float4 qv;
        float q;
        q = __fsub_rn(l4.x, rf.x);
        qv.x = __fadd_rn(l4.x, __fsub_rn(q, l4.x));
        q = __fsub_rn(l4.y, rf.y);
        qv.y = __fadd_rn(l4.y, __fsub_rn(q, l4.y));
        q = __fsub_rn(l4.z, rf.z);
        qv.z = __fadd_rn(l4.z, __fsub_rn(q, l4.z));
        q = __fsub_rn(l4.w, rf.w);
        qv.w = __fadd_rn(l4.w, __fsub_rn(q, l4.w));
        *(float4*)(rbuf + gi + j * 4) = qv;
      }
    }
  }
}

extern "C" void kernel_launch(void* const* d_in, const int* in_sizes, int n_in,
                              void* d_out, int out_size, void* d_ws,
                              size_t ws_size, hipStream_t stream) {
  const float* latent = (const float*)d_in[0];
  const float* codebooks = (const float*)d_in[1];
  float* out = (float*)d_out;
  float* C32g = (float*)d_ws;                                    // 32 KB
  unsigned short* cbf = (unsigned short*)((char*)d_ws + 32768);  // 4 MB

  float* rbuf = out;                        // residual between levels
  float* codes_out = out + (size_t)NTOK * DIM;

  hipLaunchKernelGGL(c2_kernel, dim3(DEPTH * KCB / 256), dim3(256), 0, stream,
                     codebooks, C32g);
  hipLaunchKernelGGL(pack_kernel, dim3(DEPTH * 64 * 8 * 64 / 256), dim3(256),
                     0, stream, codebooks, cbf);
  for (int lvl = 0; lvl < DEPTH; ++lvl) {
    hipLaunchKernelGGL(rvq_level_kernel, dim3(NTOK / TM), dim3(256), 0, stream,
                       latent, codebooks, C32g, cbf, rbuf, codes_out, lvl);
  }
}

// Round 18
// 2001.820 us; speedup vs baseline: 1.5151x; 1.5151x over previous
//
#include <hip/hip_runtime.h>

// Residual VQ — bf16-MFMA screen + np-exact rescore. Round 18: monolithic
// again (r17 level-split regressed); attack intra-block latency:
//  (1) software-pipelined s-loop: acc[4], ping-pong bv[2][4] + a0[2] so next
//      s-iter's global loads issue before current MFMAs (~74 VGPR <= 85 cap
//      via launch_bounds(256,6); 3 waves/SIMD).
//  (2) barrier-free passes: shared atomicMin (ordered-uint key) maintains
//      gmin; appends vs stale (>= final) gmin = superset admission (safe);
//      3 barriers/level instead of 9.
//  (3) WWIN 0.12 (~60 sigma), parallel 16-lane A_s (same np add tree).
// Decision arithmetic byte-identical to r14-r17 PASS.

#define NTOK 131072
#define DEPTH 8
#define KCB 1024
#define DIM 256
#define TM 16
#define RP 260
#define RBP 264
#define WWIN 0.12f
#define ALARM 0.05f
#define LCAP 64

typedef __attribute__((ext_vector_type(8))) short short8v;
typedef __attribute__((ext_vector_type(4))) float f32x4;

__device__ __forceinline__ unsigned short f32_to_bf16_rne(float f) {
  unsigned int u = __float_as_uint(f);
  return (unsigned short)((u + 0x7FFFu + ((u >> 16) & 1u)) >> 16);
}

__device__ __forceinline__ unsigned int fkey(float f) {
  unsigned int b = __float_as_uint(f);
  return (b & 0x80000000u) ? ~b : (b | 0x80000000u);
}
__device__ __forceinline__ float finv(unsigned int k) {
  return (k & 0x80000000u) ? __uint_as_float(k ^ 0x80000000u)
                           : __uint_as_float(~k);
}

__device__ __forceinline__ float np_sumsq_128(const float* p) {
  float s[16];
#pragma unroll
  for (int l = 0; l < 16; ++l) {
    float r0 = __fadd_rn(__fmul_rn(p[l], p[l]),
                         __fmul_rn(p[l + 64], p[l + 64]));
    float r1 = __fadd_rn(__fmul_rn(p[l + 16], p[l + 16]),
                         __fmul_rn(p[l + 80], p[l + 80]));
    float r2 = __fadd_rn(__fmul_rn(p[l + 32], p[l + 32]),
                         __fmul_rn(p[l + 96], p[l + 96]));
    float r3 = __fadd_rn(__fmul_rn(p[l + 48], p[l + 48]),
                         __fmul_rn(p[l + 112], p[l + 112]));
    s[l] = __fadd_rn(__fadd_rn(r0, r1), __fadd_rn(r2, r3));
  }
  float t[8];
#pragma unroll
  for (int l = 0; l < 8; ++l) t[l] = __fadd_rn(s[l], s[l + 8]);
  float u[4];
#pragma unroll
  for (int l = 0; l < 4; ++l) u[l] = __fadd_rn(t[l], t[l + 4]);
  return __fadd_rn(__fadd_rn(u[0], u[2]), __fadd_rn(u[1], u[3]));
}

__device__ __forceinline__ float np_sumsq_256(const float* p) {
  return __fadd_rn(np_sumsq_128(p), np_sumsq_128(p + 128));
}

// 16-lane-parallel replica of np_sumsq_256's exact add tree.
// All 16 lanes of a group call; result valid on lane kc==0.
__device__ __forceinline__ float np_sumsq_256_par(const float* p, int kc) {
  float half[2];
#pragma unroll
  for (int h = 0; h < 2; ++h) {
    const float* q = p + h * 128;
    float r0 = __fadd_rn(__fmul_rn(q[kc], q[kc]),
                         __fmul_rn(q[kc + 64], q[kc + 64]));
    float r1 = __fadd_rn(__fmul_rn(q[kc + 16], q[kc + 16]),
                         __fmul_rn(q[kc + 80], q[kc + 80]));
    float r2 = __fadd_rn(__fmul_rn(q[kc + 32], q[kc + 32]),
                         __fmul_rn(q[kc + 96], q[kc + 96]));
    float r3 = __fadd_rn(__fmul_rn(q[kc + 48], q[kc + 48]),
                         __fmul_rn(q[kc + 112], q[kc + 112]));
    float s = __fadd_rn(__fadd_rn(r0, r1), __fadd_rn(r2, r3));
    float t = __fadd_rn(s, __shfl_down(s, 8, 16));
    float u = __fadd_rn(t, __shfl_down(t, 4, 16));
    float v = __fadd_rn(u, __shfl_down(u, 2, 16));  // lane0:u0+u2 lane1:u1+u3
    half[h] = __fadd_rn(v, __shfl_down(v, 1, 16));
  }
  return __fadd_rn(half[0], half[1]);
}

__device__ __forceinline__ float np_dist(const float* rrow, const float* crow,
                                         float A, float C) {
  float dot = 0.f;
#pragma unroll 8
  for (int q = 0; q < 64; ++q) {
    float4 rv = *(const float4*)(rrow + q * 4);
    float4 cv = *(const float4*)(crow + q * 4);
    dot = fmaf(rv.x, cv.x, dot);
    dot = fmaf(rv.y, cv.y, dot);
    dot = fmaf(rv.z, cv.z, dot);
    dot = fmaf(rv.w, cv.w, dot);
  }
  return __fadd_rn(__fsub_rn(A, __fmul_rn(2.0f, dot)), C);
}

__global__ __launch_bounds__(256) void c2_kernel(const float* __restrict__ cbs,
                                                 float* __restrict__ C32g) {
  int gid = blockIdx.x * 256 + threadIdx.x;
  C32g[gid] = np_sumsq_256(cbs + (size_t)gid * DIM);
}

// cbf[(((lvl*64+g)*8+s)*64+lane)*8 + j] = bf16(cbs[lvl][g*16+(lane&15)]
//                                              [s*32+(lane>>4)*8+j])
__global__ __launch_bounds__(256) void pack_kernel(
    const float* __restrict__ cbs, unsigned short* __restrict__ cbf) {
  int gid = blockIdx.x * 256 + threadIdx.x;  // 262144
  int lane = gid & 63;
  int s = (gid >> 6) & 7;
  int g = (gid >> 9) & 63;
  int lvl = gid >> 15;
  int kcol = g * 16 + (lane & 15);
  int kd0 = s * 32 + (lane >> 4) * 8;
  const float* src = cbs + ((size_t)lvl * KCB + kcol) * DIM + kd0;
  unsigned short t[8];
#pragma unroll
  for (int j = 0; j < 8; ++j) t[j] = f32_to_bf16_rne(src[j]);
  ushort4 lo = {t[0], t[1], t[2], t[3]};
  ushort4 hi = {t[4], t[5], t[6], t[7]};
  *(ushort4*)(cbf + (size_t)gid * 8) = lo;
  *(ushort4*)(cbf + (size_t)gid * 8 + 4) = hi;
}

__global__ __launch_bounds__(256, 6) void rvq_kernel(
    const float* __restrict__ latent, const float* __restrict__ cbs,
    const float* __restrict__ C32g, const unsigned short* __restrict__ cbf,
    float* __restrict__ out) {
  __shared__ float r_m[TM][RP];
  __shared__ __align__(16) unsigned short rb[TM * RBP];
  __shared__ float A_s[TM];
  __shared__ unsigned int gkey[TM];
  __shared__ int cnt[TM];
  __shared__ int list[TM][LCAP];
  __shared__ int idx_s[TM];

  const int tid = threadIdx.x;
  const int w = tid >> 6;
  const int lane = tid & 63;
  const int lc = lane & 15;
  const int lg = lane >> 4;
  const int n0 = blockIdx.x * TM;

  // ---- stage latent -> r_m (exact) + rb (bf16); init gmin/cnt ----
  {
    int tok = tid >> 4;
    int db = (tid & 15) * 16;
    const float* src = latent + (size_t)(n0 + tok) * DIM + db;
#pragma unroll
    for (int j = 0; j < 4; ++j) {
      float4 v = *(const float4*)(src + j * 4);
      *(float4*)&r_m[tok][db + j * 4] = v;
      rb[tok * RBP + db + j * 4 + 0] = f32_to_bf16_rne(v.x);
      rb[tok * RBP + db + j * 4 + 1] = f32_to_bf16_rne(v.y);
      rb[tok * RBP + db + j * 4 + 2] = f32_to_bf16_rne(v.z);
      rb[tok * RBP + db + j * 4 + 3] = f32_to_bf16_rne(v.w);
    }
    if (tid < TM) {
      gkey[tid] = 0xFFFFFFFFu;
      cnt[tid] = 0;
    }
  }
  __syncthreads();

  for (int lvl = 0; lvl < DEPTH; ++lvl) {
    const float* cb = cbs + (size_t)lvl * KCB * DIM;

    // exact A, 16-lane-parallel np tree (visible to rescore via barrier)
    {
      float A = np_sumsq_256_par(&r_m[tid >> 4][0], tid & 15);
      if ((tid & 15) == 0) A_s[tid >> 4] = A;
    }

    // ---- 4 screen passes, barrier-free (atomicMin gmin, superset appends)
#pragma unroll 1
    for (int p = 0; p < 4; ++p) {
      f32x4 acc[4];
#pragma unroll
      for (int nt = 0; nt < 4; ++nt) acc[nt] = (f32x4){0.f, 0.f, 0.f, 0.f};

      const int kt0 = p * 16 + w * 4;  // first of 4 k-tiles this pass
      const unsigned short* bp0 =
          cbf + ((((size_t)lvl * 64 + kt0) * 8) * 64 + lane) * 8;
      // per-nt stride: 8*64*8 shorts; per-s stride: 64*8 shorts
      short8v a0c = *(const short8v*)&rb[lc * RBP + lg * 8];
      short8v b0c = *(const short8v*)(bp0 + 0 * 4096);
      short8v b1c = *(const short8v*)(bp0 + 1 * 4096);
      short8v b2c = *(const short8v*)(bp0 + 2 * 4096);
      short8v b3c = *(const short8v*)(bp0 + 3 * 4096);
#pragma unroll
      for (int s = 0; s < 8; ++s) {
        short8v a0n, b0n, b1n, b2n, b3n;
        if (s < 7) {  // issue next s-iter's loads before current MFMAs
          a0n = *(const short8v*)&rb[lc * RBP + (s + 1) * 32 + lg * 8];
          const unsigned short* bs = bp0 + (size_t)(s + 1) * 512;
          b0n = *(const short8v*)(bs + 0 * 4096);
          b1n = *(const short8v*)(bs + 1 * 4096);
          b2n = *(const short8v*)(bs + 2 * 4096);
          b3n = *(const short8v*)(bs + 3 * 4096);
        }
        acc[0] = __builtin_amdgcn_mfma_f32_16x16x32_bf16(a0c, b0c, acc[0], 0, 0, 0);
        acc[1] = __builtin_amdgcn_mfma_f32_16x16x32_bf16(a0c, b1c, acc[1], 0, 0, 0);
        acc[2] = __builtin_amdgcn_mfma_f32_16x16x32_bf16(a0c, b2c, acc[2], 0, 0, 0);
        acc[3] = __builtin_amdgcn_mfma_f32_16x16x32_bf16(a0c, b3c, acc[3], 0, 0, 0);
        if (s < 7) {
          a0c = a0n;
          b0c = b0n;
          b1c = b1n;
          b2c = b2n;
          b3c = b3n;
        }
      }

      // transform to s~ = C - 2*dot; per-token mins
      float tmin[4];
#pragma unroll
      for (int reg = 0; reg < 4; ++reg) tmin[reg] = 3.4e38f;
#pragma unroll
      for (int nt = 0; nt < 4; ++nt) {
        float Cv = C32g[lvl * KCB + (kt0 + nt) * 16 + lc];
        f32x4 sc;
#pragma unroll
        for (int reg = 0; reg < 4; ++reg) {
          float v = __fsub_rn(Cv, __fmul_rn(2.0f, acc[nt][reg]));
          sc[reg] = v;
          tmin[reg] = fminf(tmin[reg], v);
        }
        acc[nt] = sc;
      }
#pragma unroll
      for (int m = 1; m <= 8; m <<= 1)
#pragma unroll
        for (int reg = 0; reg < 4; ++reg)
          tmin[reg] = fminf(tmin[reg], __shfl_xor(tmin[reg], m));
      if (lc == 0) {
#pragma unroll
        for (int reg = 0; reg < 4; ++reg)
          atomicMin(&gkey[lg * 4 + reg], fkey(tmin[reg]));
      }
      // append vs current gmin (>= final => superset admission, safe)
#pragma unroll
      for (int reg = 0; reg < 4; ++reg) {
        int t = lg * 4 + reg;
        float th = finv(gkey[t]) + WWIN;
#pragma unroll
        for (int nt = 0; nt < 4; ++nt) {
          if (acc[nt][reg] <= th) {
            int slot = atomicAdd(&cnt[t], 1);
            if (slot < LCAP) list[t][slot] = (kt0 + nt) * 16 + lc;
          }
        }
      }
    }
    __syncthreads();  // lists, gkey, A_s final

    // ---- np-exact rescore (16 threads per token) ----
    {
      int t = tid >> 4;
      int kc = tid & 15;
      float A = A_s[t];
      float gminf = finv(gkey[t]);
      int n = cnt[t];
      float bd = 3.4e38f;
      int bk = KCB;
      if (n <= LCAP) {
        for (int ci = kc; ci < n; ci += 16) {
          int k = list[t][ci];
          float d = np_dist(&r_m[t][0], cb + (size_t)k * DIM, A,
                            C32g[lvl * KCB + k]);
          if (d < bd || (d == bd && k < bk)) {
            bd = d;
            bk = k;
          }
        }
      }
#pragma unroll
      for (int m = 1; m <= 8; m <<= 1) {
        float od = __shfl_xor(bd, m);
        int ok = __shfl_xor(bk, m);
        if (od < bd || (od == bd && ok < bk)) {
          bd = od;
          bk = ok;
        }
      }
      bool redo =
          (n > LCAP) || (fabsf(__fsub_rn(bd, A) - gminf) > (WWIN - ALARM));
      if (redo) {
        bd = 3.4e38f;
        bk = KCB;
        for (int k = kc; k < KCB; k += 16) {
          float d = np_dist(&r_m[t][0], cb + (size_t)k * DIM, A,
                            C32g[lvl * KCB + k]);
          if (d < bd || (d == bd && k < bk)) {
            bd = d;
            bk = k;
          }
        }
#pragma unroll
        for (int m = 1; m <= 8; m <<= 1) {
          float od = __shfl_xor(bd, m);
          int ok = __shfl_xor(bk, m);
          if (od < bd || (od == bd && ok < bk)) {
            bd = od;
            bk = ok;
          }
        }
      }
      if (kc == 0) {
        idx_s[t] = bk;
        out[(size_t)NTOK * DIM + (size_t)lvl * NTOK + n0 + t] = (float)bk;
      }
    }
    __syncthreads();

    // ---- residual update (exact) + rb refresh + next-level inits ----
    {
      int tok = tid >> 4;
      int db = (tid & 15) * 16;
      const float* crow = cb + (size_t)idx_s[tok] * DIM + db;
#pragma unroll
      for (int j = 0; j < 4; ++j) {
        float4 cv4 = *(const float4*)(crow + j * 4);
        int d = db + j * 4;
        float x0 = __fsub_rn(r_m[tok][d + 0], cv4.x);
        float x1 = __fsub_rn(r_m[tok][d + 1], cv4.y);
        float x2 = __fsub_rn(r_m[tok][d + 2], cv4.z);
        float x3 = __fsub_rn(r_m[tok][d + 3], cv4.w);
        r_m[tok][d + 0] = x0;
        r_m[tok][d + 1] = x1;
        r_m[tok][d + 2] = x2;
        r_m[tok][d + 3] = x3;
        rb[tok * RBP + d + 0] = f32_to_bf16_rne(x0);
        rb[tok * RBP + d + 1] = f32_to_bf16_rne(x1);
        rb[tok * RBP + d + 2] = f32_to_bf16_rne(x2);
        rb[tok * RBP + d + 3] = f32_to_bf16_rne(x3);
      }
      if (tid < TM) {
        gkey[tid] = 0xFFFFFFFFu;
        cnt[tid] = 0;
      }
    }
    __syncthreads();
  }

  // ---- straight_through = fl(l + fl(q - l)), q = fl(l - r) ----
  {
    int tok = tid >> 4;
    int db = (tid & 15) * 16;
#pragma unroll
    for (int j = 0; j < 4; ++j) {
      int d = db + j * 4;
      size_t gi = (size_t)(n0 + tok) * DIM + d;
      float4 l4 = *(const float4*)(latent + gi);
      float4 qv;
      float q;
      q = __fsub_rn(l4.x, r_m[tok][d + 0]);
      qv.x = __fadd_rn(l4.x, __fsub_rn(q, l4.x));
      q = __fsub_rn(l4.y, r_m[tok][d + 1]);
      qv.y = __fadd_rn(l4.y, __fsub_rn(q, l4.y));
      q = __fsub_rn(l4.z, r_m[tok][d + 2]);
      qv.z = __fadd_rn(l4.z, __fsub_rn(q, l4.z));
      q = __fsub_rn(l4.w, r_m[tok][d + 3]);
      qv.w = __fadd_rn(l4.w, __fsub_rn(q, l4.w));
      *(float4*)(out + gi) = qv;
    }
  }
}

extern "C" void kernel_launch(void* const* d_in, const int* in_sizes, int n_in,
                              void* d_out, int out_size, void* d_ws,
                              size_t ws_size, hipStream_t stream) {
  const float* latent = (const float*)d_in[0];
  const float* codebooks = (const float*)d_in[1];
  float* out = (float*)d_out;
  float* C32g = (float*)d_ws;                                    // 32 KB
  unsigned short* cbf = (unsigned short*)((char*)d_ws + 32768);  // 4 MB

  hipLaunchKernelGGL(c2_kernel, dim3(DEPTH * KCB / 256), dim3(256), 0, stream,
                     codebooks, C32g);
  hipLaunchKernelGGL(pack_kernel, dim3(DEPTH * 64 * 8 * 64 / 256), dim3(256),
                     0, stream, codebooks, cbf);
  hipLaunchKernelGGL(rvq_kernel, dim3(NTOK / TM), dim3(256), 0, stream, latent,
                     codebooks, C32g, cbf, out);
}